// Round 9
// baseline (251.346 us; speedup 1.0000x reference)
//
#include <hip/hip_runtime.h>
#include <cmath>

// out[b] = X_b (Wq Wk^T) (X_b^T X_b) / 768^1.5   (38 GF with G-symmetry)
// R9: fuse Ht+out into ONE kernel with per-batch team barriers, at HIGH
// co-residency (fixing R2's occupancy mistake):
//   ht_out: 768 blocks = 8 teams x 96 (team=blk&7 -> one XCD). 24 KB LDS,
//     ~5 blocks/CU by VGPR -> whole grid co-resident (barrier-safe).
//     phase 1: Ht = alpha*G*P^T, 64^2 tiles single-buffer (144 tiles/team)
//     -> team abarrier (R2-proven sense-reversing, __device__ state, n=96)
//     phase 2: out = Xbf*Ht^T, 128x64 tiles single-buffer (R4's 6/CU-class
//     config; 192 tiles/team, 2/block).
//   Removes the Ht->out launch gap + device drain; team b's out starts as
//   soon as ITS Ht is done. Teams skew freely.
// prep and gemm_GP unchanged from R8 (both below the fill floor).
// MFMA bf16 16x16x32, BK=64, fp32 accum, glds width-16, XOR chunk swizzle
// (SQ_LDS_BANK_CONFLICT=0 verified). Batch bits of blockIdx -> XCD pin.

typedef __attribute__((ext_vector_type(8))) short short8;
typedef __attribute__((ext_vector_type(4))) float f32x4;

__device__ __forceinline__ unsigned short f2bf(float f) {
    union { float f; unsigned int u; } v; v.f = f;
    unsigned int u = v.u;
    return (unsigned short)((u + 0x7FFFu + ((u >> 16) & 1u)) >> 16);  // RNE
}

// ---- persistent team-barrier state (NOT in ws: ws is poison-filled) ----
__device__ unsigned g_tbar[8][64];   // per-team [0]=cnt, [16]=gen (n=96)

__device__ __forceinline__ void abarrier(unsigned* cnt, unsigned* gen, unsigned n)
{
    __syncthreads();
    if (threadIdx.x == 0) {
        __threadfence();                   // release
        unsigned g = __hip_atomic_load(gen, __ATOMIC_RELAXED, __HIP_MEMORY_SCOPE_AGENT);
        unsigned c = __hip_atomic_fetch_add(cnt, 1u, __ATOMIC_ACQ_REL, __HIP_MEMORY_SCOPE_AGENT);
        if (c == n - 1u) {
            __hip_atomic_store(cnt, 0u, __ATOMIC_RELAXED, __HIP_MEMORY_SCOPE_AGENT);
            __hip_atomic_store(gen, g + 1u, __ATOMIC_RELEASE, __HIP_MEMORY_SCOPE_AGENT);
        } else {
            while (__hip_atomic_load(gen, __ATOMIC_RELAXED, __HIP_MEMORY_SCOPE_AGENT) == g)
                __builtin_amdgcn_s_sleep(2);
        }
        __threadfence();                   // acquire
    }
    __syncthreads();
}

// ---- staging-address setup (once) + advancing glds issue (per K-step) ----
template <int NIT>
__device__ __forceinline__ void setup_stage(const unsigned short* base, int ld, int tid,
                                            const unsigned short* (&gp)[NIT])
{
    #pragma unroll
    for (int it = 0; it < NIT; ++it) {
        int slot = it * 256 + tid, r = slot >> 3, c = slot & 7;
        gp[it] = base + (size_t)r * ld + ((c ^ (r & 7)) << 3);
    }
}

template <int NIT>
__device__ __forceinline__ void stage_adv(const unsigned short* const (&gp)[NIT], int koff,
                                          unsigned short* ldsbase, int tid)
{
    #pragma unroll
    for (int it = 0; it < NIT; ++it) {
        unsigned short* lp = ldsbase + (size_t)(it * 256 + (tid & 192)) * 8;  // wave-uniform
        __builtin_amdgcn_global_load_lds(
            (__attribute__((address_space(1))) void*)(void*)(gp[it] + koff),
            (__attribute__((address_space(3))) void*)lp, 16, 0, 0);
    }
}

// ---- fragment LDS offsets (loop-invariant, computed once) ----
template <int F>
__device__ __forceinline__ void frag_offs(int wbase, int l15, int quad, int (&o)[F][2])
{
    #pragma unroll
    for (int i = 0; i < F; ++i) {
        int r = wbase + i * 16 + l15;
        o[i][0] = r * 64 + ((quad ^ (r & 7)) << 3);
        o[i][1] = r * 64 + (((quad + 4) ^ (r & 7)) << 3);
    }
}

// ---- one K-step of MFMAs from precomputed frag offsets ----
template <int FM, int FN>
__device__ __forceinline__ void mfma_frags(const unsigned short* __restrict__ Al,
                                           const unsigned short* __restrict__ Bl,
                                           const int (&oA)[FM][2], const int (&oB)[FN][2],
                                           f32x4 (&acc)[FM][FN])
{
    short8 af[FM][2], bfr[FN][2];
    #pragma unroll
    for (int i = 0; i < FM; ++i) {
        af[i][0] = *reinterpret_cast<const short8*>(&Al[oA[i][0]]);
        af[i][1] = *reinterpret_cast<const short8*>(&Al[oA[i][1]]);
    }
    #pragma unroll
    for (int i = 0; i < FN; ++i) {
        bfr[i][0] = *reinterpret_cast<const short8*>(&Bl[oB[i][0]]);
        bfr[i][1] = *reinterpret_cast<const short8*>(&Bl[oB[i][1]]);
    }
    #pragma unroll
    for (int ks = 0; ks < 2; ++ks)
        #pragma unroll
        for (int mi = 0; mi < FM; ++mi)
            #pragma unroll
            for (int ni = 0; ni < FN; ++ni)
                acc[mi][ni] = __builtin_amdgcn_mfma_f32_16x16x32_bf16(
                    af[mi][ks], bfr[ni][ks], acc[mi][ni], 0, 0, 0);
}

// ---- fp32 -> bf16 reg staging (P from fp32 W) ----
template <int ROWS>
__device__ __forceinline__ void stage_f32(const float* __restrict__ src, unsigned short* lds,
                                          int ld, int tid)
{
    #pragma unroll
    for (int it = 0; it < ROWS / 32; ++it) {
        int slot = it * 256 + tid;
        int r = slot >> 3, c = slot & 7;
        const float* gp = src + (size_t)r * ld + c * 8;
        float4 a = *reinterpret_cast<const float4*>(gp);
        float4 d = *reinterpret_cast<const float4*>(gp + 4);
        union { short8 s; unsigned short u[8]; } v;
        v.u[0] = f2bf(a.x); v.u[1] = f2bf(a.y); v.u[2] = f2bf(a.z); v.u[3] = f2bf(a.w);
        v.u[4] = f2bf(d.x); v.u[5] = f2bf(d.y); v.u[6] = f2bf(d.z); v.u[7] = f2bf(d.w);
        *reinterpret_cast<short8*>(&lds[r * 64 + ((c ^ (r & 7)) << 3)]) = v.s;
    }
}

__device__ __forceinline__ void store_c(float* C, size_t i, float v) { C[i] = v; }
__device__ __forceinline__ void store_c(unsigned short* C, size_t i, float v) { C[i] = f2bf(v); }

// C/D layout (m89-verified): col = lane&15, row = quad*4 + reg
template <int TM, int TN, typename CT>
__device__ __forceinline__ void epilogue(CT* __restrict__ C, f32x4 (&acc)[TM / 32][TN / 32],
                                         int rowBase, int colBase, int ldc, float alpha,
                                         int wr, int wc, int l15, int quad)
{
    #pragma unroll
    for (int mi = 0; mi < TM / 32; ++mi)
        #pragma unroll
        for (int ni = 0; ni < TN / 32; ++ni) {
            int col = colBase + wc + ni * 16 + l15;
            #pragma unroll
            for (int r = 0; r < 4; ++r) {
                int row = rowBase + wr + mi * 16 + quad * 4 + r;
                store_c(C, (size_t)row * ldc + col, alpha * acc[mi][ni][r]);
            }
        }
}

// ---- prep: pure transpose, 64x64 tile per block (R4/R6-verified) ----
__global__ __launch_bounds__(256)
void prep(const float* __restrict__ X, unsigned short* __restrict__ Xt,
          unsigned short* __restrict__ Xbf)
{
    __shared__ unsigned short T[64 * 64];     // 8 KB
    const int blk = blockIdx.x;
    const int b = blk & 7;                    // XCD-pinned batch
    const int tile = blk >> 3;                // 0..383
    const int s0 = (tile & 31) * 64;
    const int d0 = (tile >> 5) * 64;
    const float* Xb = X + (size_t)b * 2048 * 768;
    unsigned short* Xtb = Xt + (size_t)b * 2048 * 768;
    unsigned short* Xbb = Xbf + (size_t)b * 2048 * 768;

    const int mr = threadIdx.x >> 4;          // s micro-block 0..15
    const int mc = threadIdx.x & 15;          // d micro-block 0..15

    const float* src = &Xb[(size_t)(s0 + 4 * mr) * 768 + d0 + 4 * mc];
    float4 v0 = *reinterpret_cast<const float4*>(src);
    float4 v1 = *reinterpret_cast<const float4*>(src + 768);
    float4 v2 = *reinterpret_cast<const float4*>(src + 2 * 768);
    float4 v3 = *reinterpret_cast<const float4*>(src + 3 * 768);
    ushort4 r0 = { f2bf(v0.x), f2bf(v0.y), f2bf(v0.z), f2bf(v0.w) };
    ushort4 r1 = { f2bf(v1.x), f2bf(v1.y), f2bf(v1.z), f2bf(v1.w) };
    ushort4 r2 = { f2bf(v2.x), f2bf(v2.y), f2bf(v2.z), f2bf(v2.w) };
    ushort4 r3 = { f2bf(v3.x), f2bf(v3.y), f2bf(v3.z), f2bf(v3.w) };
    unsigned short* dstb = &Xbb[(size_t)(s0 + 4 * mr) * 768 + d0 + 4 * mc];
    *reinterpret_cast<ushort4*>(dstb)            = r0;
    *reinterpret_cast<ushort4*>(dstb + 768)      = r1;
    *reinterpret_cast<ushort4*>(dstb + 2 * 768)  = r2;
    *reinterpret_cast<ushort4*>(dstb + 3 * 768)  = r3;

    ushort4 c0 = { r0.x, r1.x, r2.x, r3.x };
    ushort4 c1 = { r0.y, r1.y, r2.y, r3.y };
    ushort4 c2 = { r0.z, r1.z, r2.z, r3.z };
    ushort4 c3 = { r0.w, r1.w, r2.w, r3.w };
    {
        int d;
        d = 4 * mc + 0; *reinterpret_cast<ushort4*>(&T[d * 64 + ((mr ^ (2 * (d & 7))) & 15) * 4]) = c0;
        d = 4 * mc + 1; *reinterpret_cast<ushort4*>(&T[d * 64 + ((mr ^ (2 * (d & 7))) & 15) * 4]) = c1;
        d = 4 * mc + 2; *reinterpret_cast<ushort4*>(&T[d * 64 + ((mr ^ (2 * (d & 7))) & 15) * 4]) = c2;
        d = 4 * mc + 3; *reinterpret_cast<ushort4*>(&T[d * 64 + ((mr ^ (2 * (d & 7))) & 15) * 4]) = c3;
    }
    __syncthreads();
    #pragma unroll
    for (int p = 0; p < 2; ++p) {
        int d  = p * 32 + (threadIdx.x >> 3);
        int q0 = 2 * (threadIdx.x & 7);
        int c  = (q0 ^ (2 * (d & 7))) & 15;
        short8 o = *reinterpret_cast<const short8*>(&T[d * 64 + c * 4]);
        *reinterpret_cast<short8*>(&Xtb[(size_t)(d0 + d) * 2048 + s0 + q0 * 4]) = o;
    }
}

// ---- G (UNSPLIT, 64^2, upper-tri + mirror, bf16 out) + P tiles (R8) ----
__global__ __launch_bounds__(256)
void gemm_GP(const unsigned short* __restrict__ Xt, unsigned short* __restrict__ G16,
             const float* __restrict__ Wq, const float* __restrict__ Wk,
             unsigned short* __restrict__ P16)
{
    __shared__ unsigned short lds[2][(64 + 64) * 64];   // 32 KB
    const int blk = blockIdx.x;
    const int tid = threadIdx.x, lane = tid & 63, wave = tid >> 6;
    const int l15 = lane & 15, quad = lane >> 4;
    const int wr = (wave >> 1) * 32, wc = (wave & 1) * 32;

    if (blk < 624) {
        const int b = blk & 7;                  // XCD-pinned
        const int u = blk >> 3;                 // 0..77 upper-tri rank of 12x12
        int ty = 0, rem = u, len = 12;
        while (rem >= len) { rem -= len; --len; ++ty; }
        const int tz = ty + rem;                // ty <= tz
        const bool diag = (ty == tz);

        const unsigned short* Xtb = Xt + (size_t)b * 768 * 2048;
        const unsigned short* A0 = Xtb + (size_t)ty * 64 * 2048;
        const unsigned short* B0 = Xtb + (size_t)tz * 64 * 2048;
        unsigned short* C = G16 + (size_t)b * 768 * 768;

        const unsigned short* gA[2]; const unsigned short* gB[2];
        setup_stage<2>(A0, 2048, tid, gA);
        setup_stage<2>(B0, 2048, tid, gB);
        int oA[2][2], oB[2][2];
        frag_offs<2>(wr, l15, quad, oA);
        frag_offs<2>(wc, l15, quad, oB);
        const int bbase = diag ? 0 : 64 * 64;   // diag reads B frags from A LDS

        f32x4 acc[2][2] = {};
        stage_adv<2>(gA, 0, &lds[0][0], tid);
        if (!diag) stage_adv<2>(gB, 0, &lds[0][64 * 64], tid);
        __syncthreads();

        const int nt = 32;                      // K = 2048
        for (int t = 0; t < nt; ++t) {
            const int cur = t & 1;
            if (t + 1 < nt) {
                stage_adv<2>(gA, (t + 1) * 64, &lds[cur ^ 1][0], tid);
                if (!diag) stage_adv<2>(gB, (t + 1) * 64, &lds[cur ^ 1][64 * 64], tid);
            }
            mfma_frags<2, 2>(&lds[cur][0], &lds[cur][bbase], oA, oB, acc);
            __syncthreads();
        }

        #pragma unroll
        for (int mi = 0; mi < 2; ++mi)
            #pragma unroll
            for (int ni = 0; ni < 2; ++ni) {
                int col = tz * 64 + wc + ni * 16 + l15;
                int row0 = ty * 64 + wr + mi * 16 + quad * 4;
                ushort4 m;
                m.x = f2bf(acc[mi][ni][0]);
                m.y = f2bf(acc[mi][ni][1]);
                m.z = f2bf(acc[mi][ni][2]);
                m.w = f2bf(acc[mi][ni][3]);
                C[(size_t)(row0 + 0) * 768 + col] = m.x;
                C[(size_t)(row0 + 1) * 768 + col] = m.y;
                C[(size_t)(row0 + 2) * 768 + col] = m.z;
                C[(size_t)(row0 + 3) * 768 + col] = m.w;
                if (!diag)
                    *reinterpret_cast<ushort4*>(&C[(size_t)col * 768 + row0]) = m;
            }
    } else {
        const int pb = blk - 624;               // 0..143: P = Wq * Wk^T
        const int ty = pb / 12, tz = pb - ty * 12;
        int oA[2][2], oB[2][2];
        frag_offs<2>(wr, l15, quad, oA);
        frag_offs<2>(wc, l15, quad, oB);
        f32x4 acc[2][2] = {};
        for (int k0 = 0; k0 < 768; k0 += 64) {
            stage_f32<64>(Wq + (size_t)ty * 64 * 768 + k0, &lds[0][0], 768, tid);
            stage_f32<64>(Wk + (size_t)tz * 64 * 768 + k0, &lds[0][64 * 64], 768, tid);
            __syncthreads();
            mfma_frags<2, 2>(&lds[0][0], &lds[0][64 * 64], oA, oB, acc);
            __syncthreads();
        }
        epilogue<64, 64, unsigned short>(P16, acc, ty * 64, tz * 64, 768, 1.0f,
                                         wr, wc, l15, quad);
    }
}

// ---- ht_out: fused Ht (64^2) -> team barrier -> out (128x64) ----
// 768 blocks = 8 teams x 96 (team = blk&7). 24 KB LDS, all co-resident.
__global__ __launch_bounds__(256)
void ht_out(const unsigned short* __restrict__ G16, const unsigned short* __restrict__ P16,
            unsigned short* __restrict__ Ht, const unsigned short* __restrict__ Xbf,
            float* __restrict__ out, float alpha)
{
    __shared__ unsigned short lds[(128 + 64) * 64];     // 24 KB (union of phases)
    const int blk = blockIdx.x;
    const int b  = blk & 7;                  // team / batch (one XCD)
    const int lr = blk >> 3;                 // 0..95 rank in team
    const int tid = threadIdx.x, lane = tid & 63, wave = tid >> 6;
    const int l15 = lane & 15, quad = lane >> 4;

    // ---- phase 1: Ht = alpha * G * P^T, 64^2 tiles (144/team) ----
    {
        const int wr = (wave >> 1) * 32, wc = (wave & 1) * 32;
        int oA[2][2], oB[2][2];
        frag_offs<2>(wr, l15, quad, oA);
        frag_offs<2>(wc, l15, quad, oB);
        const int nrep = (lr < 48) ? 2 : 1;
        for (int rep = 0; rep < nrep; ++rep) {
            const int u = lr + rep * 96;     // 0..143
            const int ty = u / 12, tz = u - (u / 12) * 12;
            const unsigned short* A0 = G16 + (size_t)b * 768 * 768 + (size_t)ty * 64 * 768;
            const unsigned short* B0 = P16 + (size_t)tz * 64 * 768;
            const unsigned short* gA[2]; const unsigned short* gB[2];
            setup_stage<2>(A0, 768, tid, gA);
            setup_stage<2>(B0, 768, tid, gB);
            f32x4 acc[2][2] = {};
            for (int k0 = 0; k0 < 768; k0 += 64) {
                stage_adv<2>(gA, k0, lds, tid);
                stage_adv<2>(gB, k0, lds + 64 * 64, tid);
                __syncthreads();
                mfma_frags<2, 2>(lds, lds + 64 * 64, oA, oB, acc);
                __syncthreads();
            }
            epilogue<64, 64, unsigned short>(Ht + (size_t)b * 768 * 768, acc,
                                             ty * 64, tz * 64, 768, alpha,
                                             wr, wc, l15, quad);
        }
    }

    // ---- team barrier: Ht_b visible to team b ----
    abarrier(&g_tbar[b][0], &g_tbar[b][16], 96);

    // ---- phase 2: out = Xbf * Ht^T, 128x64 tiles (192/team, 2/block) ----
    {
        const int wr = (wave >> 1) * 64, wc = (wave & 1) * 32;
        int oA[4][2], oB[2][2];
        frag_offs<4>(wr, l15, quad, oA);
        frag_offs<2>(wc, l15, quad, oB);
        #pragma unroll
        for (int rep = 0; rep < 2; ++rep) {
            const int u = lr + rep * 96;     // 0..191
            const int ty = u / 12, tz = u - (u / 12) * 12;
            const unsigned short* A0 = Xbf + (size_t)b * 2048 * 768 + (size_t)ty * 128 * 768;
            const unsigned short* B0 = Ht + (size_t)b * 768 * 768 + (size_t)tz * 64 * 768;
            const unsigned short* gA[4]; const unsigned short* gB[2];
            setup_stage<4>(A0, 768, tid, gA);
            setup_stage<2>(B0, 768, tid, gB);
            f32x4 acc[4][2] = {};
            for (int k0 = 0; k0 < 768; k0 += 64) {
                stage_adv<4>(gA, k0, lds, tid);
                stage_adv<2>(gB, k0, lds + 128 * 64, tid);
                __syncthreads();
                mfma_frags<4, 2>(lds, lds + 128 * 64, oA, oB, acc);
                __syncthreads();
            }
            epilogue<128, 64, float>(out + (size_t)b * 2048 * 768, acc,
                                     ty * 128, tz * 64, 768, 1.0f,
                                     wr, wc, l15, quad);
        }
    }
}

extern "C" void kernel_launch(void* const* d_in, const int* in_sizes, int n_in,
                              void* d_out, int out_size, void* d_ws, size_t ws_size,
                              hipStream_t stream)
{
    const float* X  = (const float*)d_in[0];  // [8,2048,768] fp32
    const float* Wq = (const float*)d_in[2];  // [768,768]
    const float* Wk = (const float*)d_in[3];  // [768,768]
    float* out = (float*)d_out;               // [8,2048,768] fp32

    const int Bn = 8, S = 2048, D = 768;
    const float alpha = 1.0f / (768.0f * sqrtf(768.0f));  // 1/768^1.5
    const size_t szX  = (size_t)Bn * S * D;   // ushort elements
    const size_t szDD = (size_t)Bn * D * D;

    // ws: Xt | Xbf | P16 | G16(bf16) | Ht  (~67 MB)
    unsigned short* Xt  = (unsigned short*)d_ws;
    unsigned short* Xbf = Xt + szX;
    unsigned short* P16 = Xbf + szX;
    unsigned short* G16 = P16 + (size_t)D * D;
    unsigned short* Ht  = G16 + szDD;

    // prep: pure transpose, 3072 blocks
    prep<<<dim3(Bn * (S / 64) * (D / 64)), 256, 0, stream>>>(X, Xt, Xbf);

    // G unsplit 64^2 upper-tri (624) + P tiles (144): 768 blocks = 3/CU
    gemm_GP<<<dim3(768), 256, 0, stream>>>(Xt, G16, Wq, Wk, P16);

    // fused Ht -> team barrier -> out: 768 blocks, all co-resident
    ht_out<<<dim3(768), 256, 0, stream>>>(G16, P16, Ht, Xbf, out, alpha);
}

// Round 10
// 179.947 us; speedup vs baseline: 1.3968x; 1.3968x over previous
//
#include <hip/hip_runtime.h>
#include <cmath>

// out[b] = X_b (Wq Wk^T) (X_b^T X_b) / 768^1.5   (38 GF with G-symmetry)
// R10: revert R9's fusion (122us vs 52us separate -- third strike for
// barrier-fusion/serialization; stream-ordered fat-grid kernels win).
// = R8 (verified best, 180.6us) with ONE change: gemm_out back to the
// R3/R4-class config -- 128x64 tiles, SINGLE-buffer 24 KB, grid
// (8,16,12)=1536 = ~6 blocks/CU. R6 showed 128^2 @2/CU is latency-bound
// with every pipe idle (MfmaUtil 15%, VALU 6%, HBM 23%); co-residency is
// the proven lever (R2/R7/R9 counterexamples).
//   prep : pure transpose (3072 blocks, vectorized+swizzled, verified)
//   G+P  : G unsplit 64^2 upper-tri+mirror bf16 (dbuf 32 KB); P = Wq*Wk^T
//   Ht   : alpha*G*P^T, 96^2 all-bf16 glds, depth-2 dbuf 48 KB
//   out  : Xbf*Ht^T, 128x64 single-buffer 24 KB, 6/CU
// MFMA bf16 16x16x32, BK=64, fp32 accum, glds width-16, XOR chunk swizzle
// (SQ_LDS_BANK_CONFLICT=0 verified). Batch bits of blockIdx -> XCD pin.

typedef __attribute__((ext_vector_type(8))) short short8;
typedef __attribute__((ext_vector_type(4))) float f32x4;

__device__ __forceinline__ unsigned short f2bf(float f) {
    union { float f; unsigned int u; } v; v.f = f;
    unsigned int u = v.u;
    return (unsigned short)((u + 0x7FFFu + ((u >> 16) & 1u)) >> 16);  // RNE
}

// ---- staging-address setup (once) + advancing glds issue (per K-step) ----
template <int NIT>
__device__ __forceinline__ void setup_stage(const unsigned short* base, int ld, int tid,
                                            const unsigned short* (&gp)[NIT])
{
    #pragma unroll
    for (int it = 0; it < NIT; ++it) {
        int slot = it * 256 + tid, r = slot >> 3, c = slot & 7;
        gp[it] = base + (size_t)r * ld + ((c ^ (r & 7)) << 3);
    }
}

template <int NIT>
__device__ __forceinline__ void stage_adv(const unsigned short* const (&gp)[NIT], int koff,
                                          unsigned short* ldsbase, int tid)
{
    #pragma unroll
    for (int it = 0; it < NIT; ++it) {
        unsigned short* lp = ldsbase + (size_t)(it * 256 + (tid & 192)) * 8;  // wave-uniform
        __builtin_amdgcn_global_load_lds(
            (__attribute__((address_space(1))) void*)(void*)(gp[it] + koff),
            (__attribute__((address_space(3))) void*)lp, 16, 0, 0);
    }
}

// ---- fragment LDS offsets (loop-invariant, computed once) ----
template <int F>
__device__ __forceinline__ void frag_offs(int wbase, int l15, int quad, int (&o)[F][2])
{
    #pragma unroll
    for (int i = 0; i < F; ++i) {
        int r = wbase + i * 16 + l15;
        o[i][0] = r * 64 + ((quad ^ (r & 7)) << 3);
        o[i][1] = r * 64 + (((quad + 4) ^ (r & 7)) << 3);
    }
}

// ---- one K-step of MFMAs from precomputed frag offsets ----
template <int FM, int FN>
__device__ __forceinline__ void mfma_frags(const unsigned short* __restrict__ Al,
                                           const unsigned short* __restrict__ Bl,
                                           const int (&oA)[FM][2], const int (&oB)[FN][2],
                                           f32x4 (&acc)[FM][FN])
{
    short8 af[FM][2], bfr[FN][2];
    #pragma unroll
    for (int i = 0; i < FM; ++i) {
        af[i][0] = *reinterpret_cast<const short8*>(&Al[oA[i][0]]);
        af[i][1] = *reinterpret_cast<const short8*>(&Al[oA[i][1]]);
    }
    #pragma unroll
    for (int i = 0; i < FN; ++i) {
        bfr[i][0] = *reinterpret_cast<const short8*>(&Bl[oB[i][0]]);
        bfr[i][1] = *reinterpret_cast<const short8*>(&Bl[oB[i][1]]);
    }
    #pragma unroll
    for (int ks = 0; ks < 2; ++ks)
        #pragma unroll
        for (int mi = 0; mi < FM; ++mi)
            #pragma unroll
            for (int ni = 0; ni < FN; ++ni)
                acc[mi][ni] = __builtin_amdgcn_mfma_f32_16x16x32_bf16(
                    af[mi][ks], bfr[ni][ks], acc[mi][ni], 0, 0, 0);
}

// ---- fp32 -> bf16 reg staging (P from fp32 W) ----
template <int ROWS>
__device__ __forceinline__ void stage_f32(const float* __restrict__ src, unsigned short* lds,
                                          int ld, int tid)
{
    #pragma unroll
    for (int it = 0; it < ROWS / 32; ++it) {
        int slot = it * 256 + tid;
        int r = slot >> 3, c = slot & 7;
        const float* gp = src + (size_t)r * ld + c * 8;
        float4 a = *reinterpret_cast<const float4*>(gp);
        float4 d = *reinterpret_cast<const float4*>(gp + 4);
        union { short8 s; unsigned short u[8]; } v;
        v.u[0] = f2bf(a.x); v.u[1] = f2bf(a.y); v.u[2] = f2bf(a.z); v.u[3] = f2bf(a.w);
        v.u[4] = f2bf(d.x); v.u[5] = f2bf(d.y); v.u[6] = f2bf(d.z); v.u[7] = f2bf(d.w);
        *reinterpret_cast<short8*>(&lds[r * 64 + ((c ^ (r & 7)) << 3)]) = v.s;
    }
}

__device__ __forceinline__ void store_c(float* C, size_t i, float v) { C[i] = v; }
__device__ __forceinline__ void store_c(unsigned short* C, size_t i, float v) { C[i] = f2bf(v); }

// C/D layout (m89-verified): col = lane&15, row = quad*4 + reg
template <int TM, int TN, typename CT>
__device__ __forceinline__ void epilogue(CT* __restrict__ C, f32x4 (&acc)[TM / 32][TN / 32],
                                         int rowBase, int colBase, int ldc, float alpha,
                                         int wr, int wc, int l15, int quad)
{
    #pragma unroll
    for (int mi = 0; mi < TM / 32; ++mi)
        #pragma unroll
        for (int ni = 0; ni < TN / 32; ++ni) {
            int col = colBase + wc + ni * 16 + l15;
            #pragma unroll
            for (int r = 0; r < 4; ++r) {
                int row = rowBase + wr + mi * 16 + quad * 4 + r;
                store_c(C, (size_t)row * ldc + col, alpha * acc[mi][ni][r]);
            }
        }
}

// ---- prep: pure transpose, 64x64 tile per block (R4/R6-verified) ----
__global__ __launch_bounds__(256)
void prep(const float* __restrict__ X, unsigned short* __restrict__ Xt,
          unsigned short* __restrict__ Xbf)
{
    __shared__ unsigned short T[64 * 64];     // 8 KB
    const int blk = blockIdx.x;
    const int b = blk & 7;                    // XCD-pinned batch
    const int tile = blk >> 3;                // 0..383
    const int s0 = (tile & 31) * 64;
    const int d0 = (tile >> 5) * 64;
    const float* Xb = X + (size_t)b * 2048 * 768;
    unsigned short* Xtb = Xt + (size_t)b * 2048 * 768;
    unsigned short* Xbb = Xbf + (size_t)b * 2048 * 768;

    const int mr = threadIdx.x >> 4;          // s micro-block 0..15
    const int mc = threadIdx.x & 15;          // d micro-block 0..15

    const float* src = &Xb[(size_t)(s0 + 4 * mr) * 768 + d0 + 4 * mc];
    float4 v0 = *reinterpret_cast<const float4*>(src);
    float4 v1 = *reinterpret_cast<const float4*>(src + 768);
    float4 v2 = *reinterpret_cast<const float4*>(src + 2 * 768);
    float4 v3 = *reinterpret_cast<const float4*>(src + 3 * 768);
    ushort4 r0 = { f2bf(v0.x), f2bf(v0.y), f2bf(v0.z), f2bf(v0.w) };
    ushort4 r1 = { f2bf(v1.x), f2bf(v1.y), f2bf(v1.z), f2bf(v1.w) };
    ushort4 r2 = { f2bf(v2.x), f2bf(v2.y), f2bf(v2.z), f2bf(v2.w) };
    ushort4 r3 = { f2bf(v3.x), f2bf(v3.y), f2bf(v3.z), f2bf(v3.w) };
    unsigned short* dstb = &Xbb[(size_t)(s0 + 4 * mr) * 768 + d0 + 4 * mc];
    *reinterpret_cast<ushort4*>(dstb)            = r0;
    *reinterpret_cast<ushort4*>(dstb + 768)      = r1;
    *reinterpret_cast<ushort4*>(dstb + 2 * 768)  = r2;
    *reinterpret_cast<ushort4*>(dstb + 3 * 768)  = r3;

    ushort4 c0 = { r0.x, r1.x, r2.x, r3.x };
    ushort4 c1 = { r0.y, r1.y, r2.y, r3.y };
    ushort4 c2 = { r0.z, r1.z, r2.z, r3.z };
    ushort4 c3 = { r0.w, r1.w, r2.w, r3.w };
    {
        int d;
        d = 4 * mc + 0; *reinterpret_cast<ushort4*>(&T[d * 64 + ((mr ^ (2 * (d & 7))) & 15) * 4]) = c0;
        d = 4 * mc + 1; *reinterpret_cast<ushort4*>(&T[d * 64 + ((mr ^ (2 * (d & 7))) & 15) * 4]) = c1;
        d = 4 * mc + 2; *reinterpret_cast<ushort4*>(&T[d * 64 + ((mr ^ (2 * (d & 7))) & 15) * 4]) = c2;
        d = 4 * mc + 3; *reinterpret_cast<ushort4*>(&T[d * 64 + ((mr ^ (2 * (d & 7))) & 15) * 4]) = c3;
    }
    __syncthreads();
    #pragma unroll
    for (int p = 0; p < 2; ++p) {
        int d  = p * 32 + (threadIdx.x >> 3);
        int q0 = 2 * (threadIdx.x & 7);
        int c  = (q0 ^ (2 * (d & 7))) & 15;
        short8 o = *reinterpret_cast<const short8*>(&T[d * 64 + c * 4]);
        *reinterpret_cast<short8*>(&Xtb[(size_t)(d0 + d) * 2048 + s0 + q0 * 4]) = o;
    }
}

// ---- G (UNSPLIT, 64^2, upper-tri + mirror, bf16 out) + P tiles (R8) ----
__global__ __launch_bounds__(256)
void gemm_GP(const unsigned short* __restrict__ Xt, unsigned short* __restrict__ G16,
             const float* __restrict__ Wq, const float* __restrict__ Wk,
             unsigned short* __restrict__ P16)
{
    __shared__ unsigned short lds[2][(64 + 64) * 64];   // 32 KB
    const int blk = blockIdx.x;
    const int tid = threadIdx.x, lane = tid & 63, wave = tid >> 6;
    const int l15 = lane & 15, quad = lane >> 4;
    const int wr = (wave >> 1) * 32, wc = (wave & 1) * 32;

    if (blk < 624) {
        const int b = blk & 7;                  // XCD-pinned
        const int u = blk >> 3;                 // 0..77 upper-tri rank of 12x12
        int ty = 0, rem = u, len = 12;
        while (rem >= len) { rem -= len; --len; ++ty; }
        const int tz = ty + rem;                // ty <= tz
        const bool diag = (ty == tz);

        const unsigned short* Xtb = Xt + (size_t)b * 768 * 2048;
        const unsigned short* A0 = Xtb + (size_t)ty * 64 * 2048;
        const unsigned short* B0 = Xtb + (size_t)tz * 64 * 2048;
        unsigned short* C = G16 + (size_t)b * 768 * 768;

        const unsigned short* gA[2]; const unsigned short* gB[2];
        setup_stage<2>(A0, 2048, tid, gA);
        setup_stage<2>(B0, 2048, tid, gB);
        int oA[2][2], oB[2][2];
        frag_offs<2>(wr, l15, quad, oA);
        frag_offs<2>(wc, l15, quad, oB);
        const int bbase = diag ? 0 : 64 * 64;   // diag reads B frags from A LDS

        f32x4 acc[2][2] = {};
        stage_adv<2>(gA, 0, &lds[0][0], tid);
        if (!diag) stage_adv<2>(gB, 0, &lds[0][64 * 64], tid);
        __syncthreads();

        const int nt = 32;                      // K = 2048
        for (int t = 0; t < nt; ++t) {
            const int cur = t & 1;
            if (t + 1 < nt) {
                stage_adv<2>(gA, (t + 1) * 64, &lds[cur ^ 1][0], tid);
                if (!diag) stage_adv<2>(gB, (t + 1) * 64, &lds[cur ^ 1][64 * 64], tid);
            }
            mfma_frags<2, 2>(&lds[cur][0], &lds[cur][bbase], oA, oB, acc);
            __syncthreads();
        }

        #pragma unroll
        for (int mi = 0; mi < 2; ++mi)
            #pragma unroll
            for (int ni = 0; ni < 2; ++ni) {
                int col = tz * 64 + wc + ni * 16 + l15;
                int row0 = ty * 64 + wr + mi * 16 + quad * 4;
                ushort4 m;
                m.x = f2bf(acc[mi][ni][0]);
                m.y = f2bf(acc[mi][ni][1]);
                m.z = f2bf(acc[mi][ni][2]);
                m.w = f2bf(acc[mi][ni][3]);
                C[(size_t)(row0 + 0) * 768 + col] = m.x;
                C[(size_t)(row0 + 1) * 768 + col] = m.y;
                C[(size_t)(row0 + 2) * 768 + col] = m.z;
                C[(size_t)(row0 + 3) * 768 + col] = m.w;
                if (!diag)
                    *reinterpret_cast<ushort4*>(&C[(size_t)col * 768 + row0]) = m;
            }
    } else {
        const int pb = blk - 624;               // 0..143: P = Wq * Wk^T
        const int ty = pb / 12, tz = pb - ty * 12;
        int oA[2][2], oB[2][2];
        frag_offs<2>(wr, l15, quad, oA);
        frag_offs<2>(wc, l15, quad, oB);
        f32x4 acc[2][2] = {};
        for (int k0 = 0; k0 < 768; k0 += 64) {
            stage_f32<64>(Wq + (size_t)ty * 64 * 768 + k0, &lds[0][0], 768, tid);
            stage_f32<64>(Wk + (size_t)tz * 64 * 768 + k0, &lds[0][64 * 64], 768, tid);
            __syncthreads();
            mfma_frags<2, 2>(&lds[0][0], &lds[0][64 * 64], oA, oB, acc);
            __syncthreads();
        }
        epilogue<64, 64, unsigned short>(P16, acc, ty * 64, tz * 64, 768, 1.0f,
                                         wr, wc, l15, quad);
    }
}

// ---- Ht = alpha * G * P^T ; 96^2 all-bf16 glds, depth-2 dbuf (R8) ----
__global__ __launch_bounds__(256)
void gemm_Ht(const unsigned short* __restrict__ G16, const unsigned short* __restrict__ P16,
             unsigned short* __restrict__ Ht, float alpha)
{
    __shared__ unsigned short lds[2][(96 + 96) * 64];   // 48 KB
    const int b = blockIdx.x, ty = blockIdx.y, tz = blockIdx.z;
    const int tid = threadIdx.x, lane = tid & 63, wave = tid >> 6;
    const int wr = (wave >> 1) * 48, wc = (wave & 1) * 48;
    const int l15 = lane & 15, quad = lane >> 4;

    const unsigned short* A0 = G16 + (size_t)b * 768 * 768 + (size_t)ty * 96 * 768;
    const unsigned short* B0 = P16 + (size_t)tz * 96 * 768;

    const unsigned short* gA[3]; const unsigned short* gB[3];
    setup_stage<3>(A0, 768, tid, gA);
    setup_stage<3>(B0, 768, tid, gB);
    int oA[3][2], oB[3][2];
    frag_offs<3>(wr, l15, quad, oA);
    frag_offs<3>(wc, l15, quad, oB);

    f32x4 acc[3][3] = {};
    stage_adv<3>(gA, 0, &lds[0][0], tid);
    stage_adv<3>(gB, 0, &lds[0][96 * 64], tid);
    __syncthreads();

    const int nt = 12;                       // K = 768
    for (int t = 0; t < nt; ++t) {
        const int cur = t & 1;
        if (t + 1 < nt) {
            stage_adv<3>(gA, (t + 1) * 64, &lds[cur ^ 1][0], tid);
            stage_adv<3>(gB, (t + 1) * 64, &lds[cur ^ 1][96 * 64], tid);
        }
        mfma_frags<3, 3>(&lds[cur][0], &lds[cur][96 * 64], oA, oB, acc);
        __syncthreads();
    }
    epilogue<96, 96, unsigned short>(Ht + (size_t)b * 768 * 768, acc,
                                     ty * 96, tz * 96, 768, alpha, wr, wc, l15, quad);
}

// ---- out = Xbf * Ht^T ; 128x64 tiles, SINGLE-buffer 24 KB, ~6/CU ----
// R3/R4-class config: co-residency is the latency-hiding mechanism.
__global__ __launch_bounds__(256)
void gemm_out(const unsigned short* __restrict__ Xbf, const unsigned short* __restrict__ Ht,
              float* __restrict__ out)
{
    __shared__ unsigned short lds[(128 + 64) * 64];  // 24 KB -> LDS cap 6/CU
    const int b = blockIdx.x, ty = blockIdx.y, tz = blockIdx.z;
    const int tid = threadIdx.x, lane = tid & 63, wave = tid >> 6;
    const int wr = (wave >> 1) * 64, wc = (wave & 1) * 32;
    const int l15 = lane & 15, quad = lane >> 4;

    const unsigned short* A0 = Xbf + (size_t)b * 2048 * 768 + (size_t)ty * 128 * 768;
    const unsigned short* B0 = Ht + (size_t)b * 768 * 768 + (size_t)tz * 64 * 768;

    const unsigned short* gA[4]; const unsigned short* gB[2];
    setup_stage<4>(A0, 768, tid, gA);
    setup_stage<2>(B0, 768, tid, gB);
    int oA[4][2], oB[2][2];
    frag_offs<4>(wr, l15, quad, oA);
    frag_offs<2>(wc, l15, quad, oB);

    f32x4 acc[4][2] = {};
    for (int k0 = 0; k0 < 768; k0 += 64) {
        stage_adv<4>(gA, k0, lds, tid);
        stage_adv<2>(gB, k0, lds + 128 * 64, tid);
        __syncthreads();
        mfma_frags<4, 2>(lds, lds + 128 * 64, oA, oB, acc);
        __syncthreads();
    }
    epilogue<128, 64, float>(out + (size_t)b * 2048 * 768, acc,
                             ty * 128, tz * 64, 768, 1.0f, wr, wc, l15, quad);
}

extern "C" void kernel_launch(void* const* d_in, const int* in_sizes, int n_in,
                              void* d_out, int out_size, void* d_ws, size_t ws_size,
                              hipStream_t stream)
{
    const float* X  = (const float*)d_in[0];  // [8,2048,768] fp32
    const float* Wq = (const float*)d_in[2];  // [768,768]
    const float* Wk = (const float*)d_in[3];  // [768,768]
    float* out = (float*)d_out;               // [8,2048,768] fp32

    const int Bn = 8, S = 2048, D = 768;
    const float alpha = 1.0f / (768.0f * sqrtf(768.0f));  // 1/768^1.5
    const size_t szX  = (size_t)Bn * S * D;   // ushort elements
    const size_t szDD = (size_t)Bn * D * D;

    // ws: Xt | Xbf | P16 | G16(bf16) | Ht  (~67 MB)
    unsigned short* Xt  = (unsigned short*)d_ws;
    unsigned short* Xbf = Xt + szX;
    unsigned short* P16 = Xbf + szX;
    unsigned short* G16 = P16 + (size_t)D * D;
    unsigned short* Ht  = G16 + szDD;

    // prep: pure transpose, 3072 blocks
    prep<<<dim3(Bn * (S / 64) * (D / 64)), 256, 0, stream>>>(X, Xt, Xbf);

    // G unsplit 64^2 upper-tri (624) + P tiles (144): 768 blocks = 3/CU
    gemm_GP<<<dim3(768), 256, 0, stream>>>(Xt, G16, Wq, Wk, P16);

    // Ht: 96^2 all-bf16, grid (8,8,8) = 512
    gemm_Ht<<<dim3(Bn, 8, 8), 256, 0, stream>>>(G16, P16, Ht, alpha);

    // out: 128x64 single-buffer, grid (8,16,12) = 1536 = ~6/CU
    gemm_out<<<dim3(Bn, S / 128, 12), 256, 0, stream>>>(Xbf, Ht, out);
}